// Round 2
// baseline (781.854 us; speedup 1.0000x reference)
//
#include <hip/hip_runtime.h>

typedef unsigned short u16;
typedef unsigned int u32;
typedef __bf16 bf16x8 __attribute__((ext_vector_type(8)));
typedef float f32x4 __attribute__((ext_vector_type(4)));
typedef unsigned int u32x4 __attribute__((ext_vector_type(4)));

// Problem constants (B=8, D=128, H=W=256, border=16, cell=8)
#define NS 6272              // samples per image set (8*28*28)
#define NCOLS 6285           // 1 + 12 + 6272
#define SCORES_OFF 0LL
#define LABELS_OFF 39419520LL
#define MASK_OFF   78839040LL
#define QLT_OFF    78845312LL

// pos offsets: (i,j), i outer loop, j inner, i^2+j^2<=9. pos_off[0]=i -> x, pos_off[1]=j -> y
__constant__ int POSX[29] = {-3,-2,-2,-2,-2,-2,-1,-1,-1,-1,-1, 0,0,0,0,0,0,0, 1,1,1,1,1, 2,2,2,2,2, 3};
__constant__ int POSY[29] = { 0,-2,-1, 0, 1, 2,-2,-1, 0, 1, 2,-3,-2,-1,0,1,2,3,-2,-1,0,1,2,-2,-1,0,1,2, 0};
// neg offsets: step 2, 49<=i^2+j^2<=64
__constant__ int NEGX[12] = {-8,-6,-6,-4,-4, 0,0, 4,4, 6,6, 8};
__constant__ int NEGY[12] = { 0,-4, 4,-6, 6,-8,8,-6,6,-4,4, 0};

__device__ inline u16 f2bf(float f) {
  u32 u = __float_as_uint(f);
  u = (u + 0x7FFFu + ((u >> 16) & 1u)) >> 16;  // RNE (inputs have no NaN)
  return (u16)u;
}

// One wave per 8x8 cell: argmax (first-occurrence) then per-sample bookkeeping.
// NOTE the reference's coordinate SWAP: _sample returns (b,x,y) unpacked as
// (b, y1, x1) -> all gathers at sample points use row=X (W-coord of max),
// col=Y (H-coord of max).
__global__ __launch_bounds__(256) void sample_kernel(
    const float* __restrict__ det1, const float* __restrict__ det2,
    const float* __restrict__ aflow, const float* __restrict__ qlt1,
    int* __restrict__ sr1, int* __restrict__ sc1,
    int* __restrict__ x2a, int* __restrict__ y2a,
    int* __restrict__ xd, int* __restrict__ yd,
    float* __restrict__ qlt1v, float* __restrict__ out) {
  int isDet2 = (blockIdx.x >= 1568);
  int cell = (blockIdx.x - (isDet2 ? 1568 : 0)) * 4 + (threadIdx.x >> 6);
  int l = threadIdx.x & 63;
  int b = cell / 784, rem = cell % 784;
  int cy = rem / 28, cx = rem % 28;
  int y = 16 + cy * 8 + (l >> 3), x = 16 + cx * 8 + (l & 7);
  const float* det = isDet2 ? det2 : det1;
  float v = det[((size_t)b << 16) + (y << 8) + x];
  int idx = l;
  #pragma unroll
  for (int off = 32; off; off >>= 1) {
    float ov = __shfl_down(v, off);
    int oi = __shfl_down(idx, off);
    if (ov > v || (ov == v && oi < idx)) { v = ov; idx = oi; }
  }
  if (l == 0) {
    int ii = idx >> 3, jj = idx & 7;
    int X = 16 + cx * 8 + jj;   // W-coordinate of cell max
    int Y = 16 + cy * 8 + ii;   // H-coordinate of cell max
    if (!isDet2) {
      // reference: y1 = X (row index), x1 = Y (col index)
      sr1[cell] = X; sc1[cell] = Y;
      float ax = aflow[((size_t)(b * 2) << 16) + (X << 8) + Y];
      float ay = aflow[((size_t)(b * 2 + 1) << 16) + (X << 8) + Y];
      int xx = (int)(ax + 0.5f);   // trunc-toward-zero after +0.5, matches astype(int32)
      int yy = (int)(ay + 0.5f);
      x2a[cell] = xx; y2a[cell] = yy;
      out[MASK_OFF + cell] = (xx >= 0 && yy >= 0 && xx < 256 && yy < 256) ? 1.0f : 0.0f;
      qlt1v[cell] = qlt1[((size_t)b << 16) + (X << 8) + Y];
    } else {
      // reference: yd = X (row index), xd = Y (col index)
      yd[cell] = X; xd[cell] = Y;
    }
  }
}

// Gather descriptors at sampled points: f32 (for exact pall) + bf16 (for MFMA GEMM).
__global__ __launch_bounds__(128) void gather_kernel(
    const float* __restrict__ des1, const float* __restrict__ des2,
    const int* __restrict__ sr1, const int* __restrict__ sc1,
    const int* __restrict__ xd, const int* __restrict__ yd,
    float* __restrict__ A_f32, u16* __restrict__ A_bf16, u16* __restrict__ D_bf16) {
  int i = blockIdx.x, c = threadIdx.x;
  if (i < NS) {
    int n = i, b = n / 784;
    int r = sr1[n], cc = sc1[n];
    float v = des1[(((size_t)b * 128 + c) << 16) + (r << 8) + cc];
    A_f32[(size_t)n * 128 + c] = v;
    A_bf16[(size_t)n * 128 + c] = f2bf(v);
  } else {
    int m = i - NS, b = m / 784;
    int r = yd[m], cc = xd[m];   // distr = des2[bd, :, yd, xd]
    float v = des2[(((size_t)b * 128 + c) << 16) + (r << 8) + cc];
    D_bf16[(size_t)m * 128 + c] = f2bf(v);
  }
}

// One wave per sample: lane<29 -> pos candidate, 29..40 -> neg candidate.
// f32 dot over 128 channels per lane; shuffle-argmax (first index) for pos.
__global__ __launch_bounds__(256) void small_scores_kernel(
    const float* __restrict__ des2, const float* __restrict__ qlt2,
    const float* __restrict__ A_f32, const int* __restrict__ x2a,
    const int* __restrict__ y2a, const float* __restrict__ qlt1v,
    float* __restrict__ out) {
  int n = blockIdx.x * 4 + (threadIdx.x >> 6);
  int l = threadIdx.x & 63;
  int b = n / 784;
  int x2 = x2a[n], y2 = y2a[n];
  int ox = 0, oy = 0;
  if (l < 29) { ox = POSX[l]; oy = POSY[l]; }
  else if (l < 41) { ox = NEGX[l - 29]; oy = NEGY[l - 29]; }
  int xc = min(max(x2 + ox, 0), 255);   // col (W) index
  int yc = min(max(y2 + oy, 0), 255);   // row (H) index
  const float* d2 = des2 + ((size_t)b << 23) + ((size_t)yc << 8) + xc;
  const float* ar = A_f32 + (size_t)n * 128;
  float acc = 0.0f;
  #pragma unroll 16
  for (int c = 0; c < 128; ++c) acc += ar[c] * d2[(size_t)c << 16];
  if (l >= 29 && l < 41) out[SCORES_OFF + (size_t)n * NCOLS + 1 + (l - 29)] = acc;
  float v = (l < 29) ? acc : -1e30f;
  int idx = l;
  #pragma unroll
  for (int off = 32; off; off >>= 1) {
    float ov = __shfl_down(v, off);
    int oi = __shfl_down(idx, off);
    if (ov > v || (ov == v && oi < idx)) { v = ov; idx = oi; }
  }
  if (l == 0) {
    out[SCORES_OFF + (size_t)n * NCOLS] = v;
    int sx = min(max(x2 + POSX[idx], 0), 255);
    int sy = min(max(y2 + POSY[idx], 0), 255);
    float q = (qlt1v[n] + qlt2[((size_t)b << 16) + (sy << 8) + sx]) * 0.5f;
    out[QLT_OFF + n] = q;
  }
}

__global__ __launch_bounds__(256) void labels_kernel(float* __restrict__ out) {
  int n = blockIdx.x * 256 + threadIdx.x;
  if (n < NS) out[LABELS_OFF + (size_t)n * NCOLS] = 1.0f;
}

// dscores GEMM: C[n,m] = sum_k A[n,k]*D[m,k], bf16 MFMA 16x16x32, 128x128 tile,
// K=128 staged once in LDS (no K loop). Fused distance-mask epilogue.
__global__ __launch_bounds__(256, 2) void gemm_kernel(
    const u16* __restrict__ A, const u16* __restrict__ Bm,
    const int* __restrict__ x2a, const int* __restrict__ y2a,
    const int* __restrict__ xd, const int* __restrict__ yd,
    float* __restrict__ out) {
  __shared__ u16 As[128 * 136];  // +8 bf16 pad per row
  __shared__ u16 Bs[128 * 136];
  int tid = threadIdx.x;
  int R = blockIdx.y, C = blockIdx.x;
  const u32x4* gA = (const u32x4*)(A + (size_t)R * 16384);
  const u32x4* gB = (const u32x4*)(Bm + (size_t)C * 16384);
  #pragma unroll
  for (int p = 0; p < 8; ++p) {
    int i = tid + p * 256;
    int r = i >> 4, kc = (i & 15) * 8;
    *(u32x4*)&As[r * 136 + kc] = gA[i];
    *(u32x4*)&Bs[r * 136 + kc] = gB[i];
  }
  __syncthreads();
  int l = tid & 63, w = tid >> 6;
  int lr = l & 15, lq = l >> 4;
  int wr = (w & 1) * 64, wc = (w >> 1) * 64;
  f32x4 acc[4][4] = {};
  #pragma unroll
  for (int kk = 0; kk < 4; ++kk) {
    bf16x8 af[4], bfr[4];
    #pragma unroll
    for (int t = 0; t < 4; ++t) {
      af[t]  = *(const bf16x8*)&As[(wr + t * 16 + lr) * 136 + kk * 32 + lq * 8];
      bfr[t] = *(const bf16x8*)&Bs[(wc + t * 16 + lr) * 136 + kk * 32 + lq * 8];
    }
    #pragma unroll
    for (int tr = 0; tr < 4; ++tr)
      #pragma unroll
      for (int tc = 0; tc < 4; ++tc)
        acc[tr][tc] = __builtin_amdgcn_mfma_f32_16x16x32_bf16(af[tr], bfr[tc], acc[tr][tc], 0, 0, 0);
  }
  #pragma unroll
  for (int tr = 0; tr < 4; ++tr) {
    int rows[4], rx[4], ry[4], rb[4];
    #pragma unroll
    for (int r = 0; r < 4; ++r) {
      int row = R * 128 + wr + tr * 16 + lq * 4 + r;
      rows[r] = row; rx[r] = x2a[row]; ry[r] = y2a[row]; rb[r] = row / 784;
    }
    #pragma unroll
    for (int tc = 0; tc < 4; ++tc) {
      int col = C * 128 + wc + tc * 16 + lr;
      int cxv = xd[col], cyv = yd[col], cb = col / 784;  // xd vs xy2[0], yd vs xy2[1]
      #pragma unroll
      for (int r = 0; r < 4; ++r) {
        int dx = cxv - rx[r], dy = cyv - ry[r];
        int dis2 = dx * dx + dy * dy + (cb != rb[r] ? 9 : 0);
        float v = acc[tr][tc][r];
        if (dis2 < 9) v = 0.0f;
        out[SCORES_OFF + (size_t)rows[r] * NCOLS + 13 + col] = v;
      }
    }
  }
}

extern "C" void kernel_launch(void* const* d_in, const int* in_sizes, int n_in,
                              void* d_out, int out_size, void* d_ws, size_t ws_size,
                              hipStream_t stream) {
  const float* des1 = (const float*)d_in[0];
  const float* det1 = (const float*)d_in[1];
  const float* qlt1 = (const float*)d_in[2];
  const float* des2 = (const float*)d_in[3];
  const float* det2 = (const float*)d_in[4];
  const float* qlt2 = (const float*)d_in[5];
  const float* aflow = (const float*)d_in[6];
  float* out = (float*)d_out;

  // workspace layout (16B-aligned blocks)
  char* ws = (char*)d_ws;
  int* sr1 = (int*)ws;                       // NS
  int* sc1 = sr1 + NS;
  int* x2a = sc1 + NS;
  int* y2a = x2a + NS;
  int* xd  = y2a + NS;
  int* yd  = xd + NS;
  float* qlt1v = (float*)(yd + NS);          // NS
  float* A_f32 = qlt1v + NS;                 // NS*128
  u16* A_bf16 = (u16*)(A_f32 + (size_t)NS * 128);  // NS*128
  u16* D_bf16 = A_bf16 + (size_t)NS * 128;         // NS*128

  // labels = zeros except col 0
  hipMemsetAsync((void*)(out + LABELS_OFF), 0, (size_t)NS * NCOLS * sizeof(float), stream);

  sample_kernel<<<3136, 256, 0, stream>>>(det1, det2, aflow, qlt1,
                                          sr1, sc1, x2a, y2a, xd, yd, qlt1v, out);
  gather_kernel<<<2 * NS, 128, 0, stream>>>(des1, des2, sr1, sc1, xd, yd,
                                            A_f32, A_bf16, D_bf16);
  small_scores_kernel<<<NS / 4, 256, 0, stream>>>(des2, qlt2, A_f32, x2a, y2a, qlt1v, out);
  labels_kernel<<<(NS + 255) / 256, 256, 0, stream>>>(out);
  dim3 g(49, 49);
  gemm_kernel<<<g, 256, 0, stream>>>(A_bf16, D_bf16, x2a, y2a, xd, yd, out);
}